// Round 10
// baseline (222.955 us; speedup 1.0000x reference)
//
#include <hip/hip_runtime.h>
#include <stdint.h>
#include <math.h>

#define HW_ 16384   // H*W = 128*128
#define C_  256
#define NT  4       // tiles per block (each tile = 128 positions)

typedef long i64;
typedef float f32x4 __attribute__((ext_vector_type(4)));
typedef long i64x2 __attribute__((ext_vector_type(2)));
typedef unsigned int u32;

// barrier WITHOUT vmcnt drain: orders LDS only; prefetch loads stay in flight
#define BARRIER_LGKM() asm volatile("s_waitcnt lgkmcnt(0)\n\ts_barrier" ::: "memory")

// -------- kernel 0: prep (W -> fp8 e4m3 in MFMA-fragment order, BN consts) --
// Wp byte layout: idx = ((ks*16 + mf)*64 + kg*16 + r15)*8 + e
__global__ __launch_bounds__(256) void k0_prep(
    const float* __restrict__ w_fe, const float* __restrict__ gamma,
    const float* __restrict__ beta, const float* __restrict__ mean,
    const float* __restrict__ var, u32* __restrict__ Wp,
    float* __restrict__ scale, float* __restrict__ shift)
{
  int i = blockIdx.x * 256 + threadIdx.x;
  if (i < 32768) {                     // one u32 = 4 fp8 bytes
    int e0  = (i & 1) * 4;
    int r15 = (i >> 1) & 15;
    int kg  = (i >> 5) & 3;
    int mf  = (i >> 7) & 15;
    int ks  = i >> 11;
    int row = mf * 16 + r15;
    int k   = ks * 32 + kg * 8 + e0;   // 4 consecutive k
    const float* src = w_fe + row * 512 + k;
    u32 w = 0;
    w = __builtin_amdgcn_cvt_pk_fp8_f32(src[0], src[1], w, false);
    w = __builtin_amdgcn_cvt_pk_fp8_f32(src[2], src[3], w, true);
    Wp[i] = w;
  }
  if (i < 256) {
    float sc = gamma[i] * rsqrtf(var[i] + 1e-5f);
    scale[i] = sc;
    shift[i] = beta[i] - mean[i] * sc;
  }
}

// ------- kernel 1: persistent-W fp8 MFMA GEMM + BN + ReLU + pool -------
// 16 waves; wave w = m-frag w. A-frags (fp8, 32 VGPRs) in regs. Tile = 128
// positions x 512 k, fp8 in LDS, frag-pair-linear (64 x 1KB blocks,
// conflict-free b128 reads), double-buffered (2 x 64KB).
// Staging: float4 loads -> one wave-load covers 2 rows x 512 B CONTIGUOUS
// (vs 256 B before) -- the X-delivery experiment. Half-tile interleaved
// prefetch; lgkm-only barrier so loads stay in flight across tiles.
__global__ __launch_bounds__(1024, 4) void k1_gemm_pool(
    const float* __restrict__ x1, const float* __restrict__ x2,
    const u32* __restrict__ Wp,
    const float* __restrict__ scale, const float* __restrict__ shift,
    float* __restrict__ pool_part)
{
  __shared__ __align__(16) char Bl[2][65536];   // 2 x 64KB

  const int tid  = threadIdx.x;
  const int wave = tid >> 6;        // = mf
  const int lane = tid & 63;
  const int r15  = lane & 15;
  const int kg   = lane >> 4;
  const int blk  = blockIdx.x;
  const int b    = blk >> 5;                 // batch
  const int tile0 = (blk & 31) * NT;

  const float* xb1 = x1 + (size_t)b * C_ * HW_;
  const float* xb2 = x2 + (size_t)b * C_ * HW_;

  // staging decomposition: thread owns k-octet k8p (8 rows) x 4 positions
  const int p4  = (tid & 31) * 4;    // position base 0..124
  const int k8p = tid >> 5;          // k-octet 0..31 within a 256-k half
  const int nfs = p4 >> 4;           // frag nf of all 4 positions (0..7)
  const int slot0 = (p4 & 15) + (k8p & 3) * 16;
  // write byte base within buffer (add H*32768 for half H):
  const int WB0 = ((k8p >> 2) * 4 + (nfs >> 1)) * 1024 + slot0 * 16
                  + (nfs & 1) * 8;

  // ---- A-frags once for this wave (16 x i64 = 32 VGPRs) ----
  i64 Af[16];
#pragma unroll
  for (int ks = 0; ks < 16; ++ks)
    Af[ks] = *(const i64*)((const char*)Wp
             + ((ks * 16 + wave) * 64 + kg * 16 + r15) * 8);

  const int chbase = wave * 16 + kg * 4;
  const float4 sc4 = *(const float4*)&scale[chbase];
  const float4 sh4 = *(const float4*)&shift[chbase];

  float pool0 = 0.f, pool1 = 0.f, pool2 = 0.f, pool3 = 0.f;

  float4 gS[8];   // staging bank: 8 k-rows x 4 positions (32 VGPRs)

// Load half H (256 k) of tile at base position P0 (8 x float4 = dwordx4).
#define ISSUE_HB(H, P0)                                                       \
  {                                                                           \
    const float* s0 = ((H) == 0 ? xb1 : xb2) + (size_t)(k8p * 8) * HW_        \
                      + (P0) + p4;                                            \
    _Pragma("unroll")                                                         \
    for (int r = 0; r < 8; ++r) gS[r] = *(const float4*)(s0 + r * HW_);       \
  }

// Convert to fp8, write 4 x b64 (one k-octet per position).
#define WRITE_HB(H, BUF)                                                      \
  {                                                                           \
    char* wb0 = (char*)(BUF) + WB0 + (H) * 32768;                             \
    _Pragma("unroll")                                                         \
    for (int i = 0; i < 4; ++i) {                                             \
      const float* gp = (const float*)gS;                                     \
      u32 w0 = 0, w1 = 0;                                                     \
      w0 = __builtin_amdgcn_cvt_pk_fp8_f32(gp[0 * 4 + i], gp[1 * 4 + i], w0, false); \
      w0 = __builtin_amdgcn_cvt_pk_fp8_f32(gp[2 * 4 + i], gp[3 * 4 + i], w0, true);  \
      w1 = __builtin_amdgcn_cvt_pk_fp8_f32(gp[4 * 4 + i], gp[5 * 4 + i], w1, false); \
      w1 = __builtin_amdgcn_cvt_pk_fp8_f32(gp[6 * 4 + i], gp[7 * 4 + i], w1, true);  \
      u32* wb = (u32*)(wb0 + i * 16);                                         \
      wb[0] = w0; wb[1] = w1;                                                 \
    }                                                                         \
  }

// 32 b128 reads (2 frags each) + 64 MFMA: input half H.
#define COMPUTE_H(H, BUF)                                                     \
  {                                                                           \
    _Pragma("unroll")                                                         \
    for (int ks8 = 0; ks8 < 8; ++ks8) {                                       \
      const int ks = (H) * 8 + ks8;                                           \
      const char* rbase = (const char*)(BUF) + ks * 4096 + lane * 16;         \
      _Pragma("unroll")                                                       \
      for (int np = 0; np < 4; ++np) {                                        \
        i64x2 bq = *(const i64x2*)(rbase + np * 1024);                        \
        acc[np * 2] = __builtin_amdgcn_mfma_f32_16x16x32_fp8_fp8(             \
            Af[ks], bq.x, acc[np * 2], 0, 0, 0);                              \
        acc[np * 2 + 1] = __builtin_amdgcn_mfma_f32_16x16x32_fp8_fp8(         \
            Af[ks], bq.y, acc[np * 2 + 1], 0, 0, 0);                          \
      }                                                                       \
    }                                                                         \
  }

  // ---- prologue: stage tile0 into buf 0 ----
  ISSUE_HB(0, tile0 * 128) WRITE_HB(0, Bl[0])
  ISSUE_HB(1, tile0 * 128) WRITE_HB(1, Bl[0])
  __syncthreads();

  for (int tt = 0; tt < NT; ++tt) {
    f32x4 acc[8];
#pragma unroll
    for (int nf = 0; nf < 8; ++nf) acc[nf] = (f32x4){0.f, 0.f, 0.f, 0.f};

    const int p0n = (tile0 + tt + 1) * 128;
    const bool more = (tt + 1 < NT);
    const char* cb = Bl[tt & 1];
    char* nxt = Bl[(tt + 1) & 1];

    if (more) ISSUE_HB(0, p0n)
    COMPUTE_H(0, cb)
    if (more) { WRITE_HB(0, nxt) ISSUE_HB(1, p0n) }
    COMPUTE_H(1, cb)
    if (more) WRITE_HB(1, nxt)

    // pool accumulate: BN + ReLU over this tile's 128 positions
#pragma unroll
    for (int nf = 0; nf < 8; ++nf) {
      pool0 += fmaxf(acc[nf][0] * sc4.x + sh4.x, 0.f);
      pool1 += fmaxf(acc[nf][1] * sc4.y + sh4.y, 0.f);
      pool2 += fmaxf(acc[nf][2] * sc4.z + sh4.z, 0.f);
      pool3 += fmaxf(acc[nf][3] * sc4.w + sh4.w, 0.f);
    }
    BARRIER_LGKM();                    // loads stay in flight across barrier
  }

  // reduce over the 16 positions (r15 lanes)
#pragma unroll
  for (int m = 1; m < 16; m <<= 1) {
    pool0 += __shfl_xor(pool0, m);
    pool1 += __shfl_xor(pool1, m);
    pool2 += __shfl_xor(pool2, m);
    pool3 += __shfl_xor(pool3, m);
  }
  if (r15 == 0) {
    float* dst = pool_part + (size_t)blk * 256 + chbase;
    dst[0] = pool0; dst[1] = pool1; dst[2] = pool2; dst[3] = pool3;
  }
}

// -------- kernel 2: tiny MLPs -> per-(b,c) 3x3 kernels + attn coefs --------
// grid 80 = 8 batches x 10 jobs (j=0..8: tap j of all 256 channels; j=9: coef)
__global__ __launch_bounds__(256) void k2_small(
    const float* __restrict__ pool_part,
    const float* __restrict__ w_cg1, const float* __restrict__ w_cg2,
    const float* __restrict__ w_ag1, const float* __restrict__ w_ag2,
    float* __restrict__ cw, float* __restrict__ coef)
{
  __shared__ float pl[256];
  __shared__ float hl[64];
  const int bi = blockIdx.x;
  const int b = bi / 10, j = bi % 10;
  const int t = threadIdx.x;
  float s = 0.f;
  const float* base = pool_part + (size_t)b * 32 * 256 + t;
  for (int blk = 0; blk < 32; ++blk) s += base[blk * 256];   // fixed order
  pl[t] = s * (1.0f / 16384.0f);
  __syncthreads();
  if (j < 9) {
    if (t < 64) {
      float h = 0.f;
      for (int i = 0; i < 256; ++i) h += pl[i] * w_cg1[t * 256 + i];
      hl[t] = fmaxf(h, 0.f);
    }
    __syncthreads();
    const int o = t * 9 + j;                 // row of w_cg2 = c*9 + tap
    float acc = 0.f;
    for (int jj = 0; jj < 64; ++jj) acc += hl[jj] * w_cg2[o * 64 + jj];
    cw[b * 2304 + o] = acc;
  } else {
    if (t < 64) {
      float a = 0.f;
      for (int i = 0; i < 256; ++i) a += pl[i] * w_ag1[t * 256 + i];
      hl[t] = fmaxf(a, 0.f);
    }
    __syncthreads();
    if (t < 2) {
      float acc = 0.f;
      for (int jj = 0; jj < 64; ++jj) acc += hl[jj] * w_ag2[t * 64 + jj];
      coef[b * 2 + t] = 0.25f / (1.0f + expf(-acc));   // 0.25 = L_S * L_C
    }
  }
}

// -------- kernel 3: depthwise 3x3 (same kernel on x1 & x2) + combine --------
__global__ __launch_bounds__(256) void k3_dynconv(
    const float* __restrict__ x1, const float* __restrict__ x2,
    const float* __restrict__ cw, const float* __restrict__ coef,
    float* __restrict__ out)
{
  __shared__ float t1[34 * 128];
  __shared__ float t2[34 * 128];
  const int tid   = threadIdx.x;
  const int blk   = blockIdx.x;
  const int strip = blk & 3;
  const int c     = (blk >> 2) & 255;
  const int b     = blk >> 10;
  const int h0    = strip * 32;

  const size_t plane = ((size_t)b * C_ + c) * HW_;
  const float* p1 = x1 + plane;
  const float* p2 = x2 + plane;

  float tp[9];
#pragma unroll
  for (int e = 0; e < 9; ++e) tp[e] = cw[(b * C_ + c) * 9 + e];
  const float c1 = coef[b * 2 + 0];
  const float c2 = coef[b * 2 + 1];

  for (int f = tid; f < 1088; f += 256) {
    int row = f >> 5;
    int c4  = (f & 31) << 2;
    int gh  = h0 - 1 + row;
    float4 v1 = make_float4(0.f, 0.f, 0.f, 0.f), v2 = v1;
    if (gh >= 0 && gh < 128) {
      v1 = *(const float4*)&p1[gh * 128 + c4];
      v2 = *(const float4*)&p2[gh * 128 + c4];
    }
    *(float4*)&t1[row * 128 + c4] = v1;
    *(float4*)&t2[row * 128 + c4] = v2;
  }
  __syncthreads();

  for (int i = 0; i < 16; ++i) {
    int q   = tid + i * 256;
    int r   = q >> 7;
    int col = q & 127;
    int lr  = r + 1;
    const bool lok = col > 0, rok = col < 127;
    float d1 = 0.f, d2 = 0.f;
#pragma unroll
    for (int dy = 0; dy < 3; ++dy) {
      const float* row1 = &t1[(lr - 1 + dy) * 128];
      const float* row2 = &t2[(lr - 1 + dy) * 128];
      float a1v = lok ? row1[col - 1] : 0.f;
      float b1v = row1[col];
      float e1v = rok ? row1[col + 1] : 0.f;
      float a2v = lok ? row2[col - 1] : 0.f;
      float b2v = row2[col];
      float e2v = rok ? row2[col + 1] : 0.f;
      d1 += a1v * tp[dy * 3 + 0] + b1v * tp[dy * 3 + 1] + e1v * tp[dy * 3 + 2];
      d2 += a2v * tp[dy * 3 + 0] + b2v * tp[dy * 3 + 1] + e2v * tp[dy * 3 + 2];
    }
    float v1 = t1[lr * 128 + col];
    float v2 = t2[lr * 128 + col];
    out[plane + (size_t)(h0 + r) * 128 + col] = 0.5f * (v1 + v2) + c1 * d1 + c2 * d2;
  }
}

extern "C" void kernel_launch(void* const* d_in, const int* in_sizes, int n_in,
                              void* d_out, int out_size, void* d_ws, size_t ws_size,
                              hipStream_t stream) {
  const float* x1    = (const float*)d_in[0];
  const float* x2    = (const float*)d_in[1];
  const float* w_fe  = (const float*)d_in[2];
  const float* gamma = (const float*)d_in[3];
  const float* beta  = (const float*)d_in[4];
  const float* mean  = (const float*)d_in[5];
  const float* var   = (const float*)d_in[6];
  const float* w_cg1 = (const float*)d_in[7];
  const float* w_cg2 = (const float*)d_in[8];
  const float* w_ag1 = (const float*)d_in[9];
  const float* w_ag2 = (const float*)d_in[10];
  float* out = (float*)d_out;

  // workspace layout (~470 KB)
  char* ws = (char*)d_ws;
  u32* Wp          = (u32*)(ws);                           // [0, 131072)
  float* scale     = (float*)(ws + 131072);                // 1 KB
  float* shift     = (float*)(ws + 132096);                // 1 KB
  float* pool_part = (float*)(ws + 133120);                // 256*256*4 = 256 KB
  float* cw        = (float*)(ws + 395264);                // 73728 B
  float* coef      = (float*)(ws + 468992);                // 64 B

  k0_prep<<<128, 256, 0, stream>>>(w_fe, gamma, beta, mean, var, Wp, scale, shift);
  k1_gemm_pool<<<256, 1024, 0, stream>>>(x1, x2, Wp, scale, shift, pool_part);
  k2_small<<<80, 256, 0, stream>>>(pool_part, w_cg1, w_cg2, w_ag1, w_ag2, cw, coef);
  k3_dynconv<<<8192, 256, 0, stream>>>(x1, x2, cw, coef, out);
}

// Round 11
// 220.855 us; speedup vs baseline: 1.0095x; 1.0095x over previous
//
#include <hip/hip_runtime.h>
#include <stdint.h>
#include <math.h>

#define HW_ 16384   // H*W = 128*128
#define C_  256

typedef long i64;
typedef float f32x4 __attribute__((ext_vector_type(4)));
typedef long i64x2 __attribute__((ext_vector_type(2)));
typedef unsigned int u32;

__device__ __forceinline__ void gload_lds16(const void* g, void* l) {
  __builtin_amdgcn_global_load_lds((const __attribute__((address_space(1))) u32*)g,
                                   (__attribute__((address_space(3))) u32*)l, 16, 0, 0);
}

// counted-vmcnt barrier: wait current tile's 4 gloads (newer 4 stay in flight)
#define VMBAR4() asm volatile("s_waitcnt vmcnt(4)\n\ts_barrier" ::: "memory")
#define VMBAR0() asm volatile("s_waitcnt vmcnt(0)\n\ts_barrier" ::: "memory")
#define BAR()    asm volatile("s_barrier" ::: "memory")

// -------- kernel 0: prep (W -> fp8 e4m3 in MFMA-fragment order, BN consts) --
// Wp byte layout: idx = ((ks*16 + mf)*64 + kg*16 + r15)*8 + e
__global__ __launch_bounds__(256) void k0_prep(
    const float* __restrict__ w_fe, const float* __restrict__ gamma,
    const float* __restrict__ beta, const float* __restrict__ mean,
    const float* __restrict__ var, u32* __restrict__ Wp,
    float* __restrict__ scale, float* __restrict__ shift)
{
  int i = blockIdx.x * 256 + threadIdx.x;
  if (i < 32768) {                     // one u32 = 4 fp8 bytes
    int e0  = (i & 1) * 4;
    int r15 = (i >> 1) & 15;
    int kg  = (i >> 5) & 3;
    int mf  = (i >> 7) & 15;
    int ks  = i >> 11;
    int row = mf * 16 + r15;
    int k   = ks * 32 + kg * 8 + e0;   // 4 consecutive k
    const float* src = w_fe + row * 512 + k;
    u32 w = 0;
    w = __builtin_amdgcn_cvt_pk_fp8_f32(src[0], src[1], w, false);
    w = __builtin_amdgcn_cvt_pk_fp8_f32(src[2], src[3], w, true);
    Wp[i] = w;
  }
  if (i < 256) {
    float sc = gamma[i] * rsqrtf(var[i] + 1e-5f);
    scale[i] = sc;
    shift[i] = beta[i] - mean[i] * sc;
  }
}

// ------- kernel q: pack X (f32, row-major) -> Xq (fp8 tile images) -------
// Xq = 1024 images of 64 KB; image (b*128+t) holds tile t (128 pos x 512 k)
// of batch b in EXACTLY k1's LDS byte order:
//   byte(k,p) = fb*1024 + slot*16 + par*8 + e,
//   fb = (k>>8)*32 + ((k>>5)&7)*4 + ((p&127)>>5), slot = (p&15)+((k>>3)&3)*16,
//   par = (p>>4)&1, e = k&7.
// Block = (batch, k-octet, pos-half): reads 8 rows sequentially (contiguous,
// m13-pattern), LDS-bounce transpose, writes 256-B bursts into images.
__global__ __launch_bounds__(256) void kq_pack(
    const float* __restrict__ x1, const float* __restrict__ x2,
    char* __restrict__ Xq)
{
  __shared__ char T[8192];
  const int tid  = threadIdx.x;
  const int bq   = blockIdx.x;        // 1024 blocks
  const int half = bq & 1;            // position half (8192 each)
  const int k8g  = (bq >> 1) & 63;    // global k-octet 0..63
  const int b    = bq >> 7;
  const int H    = k8g >> 5;          // 0: x1 rows, 1: x2 rows
  const int ko   = k8g & 31;
  const int fbb  = H * 32 + (ko >> 2) * 4;   // fb base (nf2 added later)
  const int kg   = ko & 3;

  const float* xs = (H ? x2 : x1) + ((size_t)b * C_ + ko * 8) * HW_;
  const int r  = tid >> 5;            // row within octet 0..7
  const int pc = (tid & 31) * 4;      // fine position 0..124

  const int a0base = ((pc >> 5) & 3) * 256 + (pc & 15) * 16 + ((pc >> 4) & 1) * 8 + r;

  for (int n = 0; n < 8; ++n) {
    const float* s0 = xs + (size_t)r * HW_ + half * 8192 + n * 1024 + pc;
    float4 g[8];
#pragma unroll
    for (int j = 0; j < 8; ++j) g[j] = *(const float4*)(s0 + j * 128);
    __syncthreads();                  // prev iter's phase2 done; loads drain
#pragma unroll
    for (int j = 0; j < 8; ++j) {
      u32 w0 = 0, w1 = 0;
      w0 = __builtin_amdgcn_cvt_pk_fp8_f32(g[j].x, g[j].y, w0, false);
      w1 = __builtin_amdgcn_cvt_pk_fp8_f32(g[j].z, g[j].w, w1, false);
      int a0 = j * 1024 + a0base;
      T[a0]      = (char)(w0 & 0xff);
      T[a0 + 16] = (char)((w0 >> 8) & 0xff);
      T[a0 + 32] = (char)(w1 & 0xff);
      T[a0 + 48] = (char)((w1 >> 8) & 0xff);
    }
    __syncthreads();
    // phase2: linear LDS -> 256-B bursts into tile images
#pragma unroll
    for (int q2 = 0; q2 < 2; ++q2) {
      int u = tid * 16 + q2 * 4096;
      int tloc = u >> 10, nf2 = (u >> 8) & 3, inoff = u & 255;
      char* dst = Xq + ((size_t)(b * 128 + half * 64 + n * 8 + tloc) << 16)
                  + (fbb + nf2) * 1024 + kg * 256 + inoff;
      *(float4*)dst = *(const float4*)&T[u];
    }
  }
}

// ------- kernel 1: sequential-staged fp8 MFMA GEMM + BN + ReLU + pool ------
// 16 waves; wave = m-frag. Af in regs (32 VGPR). Tile image (64 KB) staged by
// 4 global_load_lds dwordx4 per thread -- PURELY SEQUENTIAL source. Double-
// buffered; counted vmcnt(4) + raw barriers; frag-pair-linear b128 reads.
__global__ __launch_bounds__(1024, 4) void k1_gemm_pool(
    const char* __restrict__ Xq, const u32* __restrict__ Wp,
    const float* __restrict__ scale, const float* __restrict__ shift,
    float* __restrict__ pool_part)
{
  __shared__ __align__(16) char Bl[2][65536];   // 2 x 64KB

  const int tid  = threadIdx.x;
  const int wave = tid >> 6;
  const int lane = tid & 63;
  const int r15  = lane & 15;
  const int kg   = lane >> 4;
  const int blk  = blockIdx.x;
  const int b    = blk >> 5;
  const int t0   = (blk & 31) * 4;     // 4 images per block

  // ---- A-frags once for this wave (16 x i64 = 32 VGPRs) ----
  i64 Af[16];
#pragma unroll
  for (int ks = 0; ks < 16; ++ks)
    Af[ks] = *(const i64*)((const char*)Wp
             + ((ks * 16 + wave) * 64 + kg * 16 + r15) * 8);

  const int chbase = wave * 16 + kg * 4;
  const float4 sc4 = *(const float4*)&scale[chbase];
  const float4 sh4 = *(const float4*)&shift[chbase];

  float pool0 = 0.f, pool1 = 0.f, pool2 = 0.f, pool3 = 0.f;

  const int ldsw = (tid & 0xFFC0) * 16;   // wave-uniform LDS base part

#define GISSUE(I, BUF)                                                        \
  {                                                                           \
    const char* img = Xq + ((size_t)(b * 128 + t0 + (I)) << 16) + tid * 16;   \
    _Pragma("unroll")                                                         \
    for (int ps = 0; ps < 4; ++ps)                                            \
      gload_lds16(img + ps * 16384, (char*)(BUF) + ps * 16384 + ldsw);        \
  }

// 64 b128 reads (2 frags each) + 128 MFMA over the full 512-k tile.
#define COMPUTE_T(BUF)                                                        \
  {                                                                           \
    _Pragma("unroll")                                                         \
    for (int ks = 0; ks < 16; ++ks) {                                         \
      const char* rbase = (const char*)(BUF) + ks * 4096 + lane * 16;         \
      _Pragma("unroll")                                                       \
      for (int np = 0; np < 4; ++np) {                                        \
        i64x2 bq2 = *(const i64x2*)(rbase + np * 1024);                       \
        acc[np * 2] = __builtin_amdgcn_mfma_f32_16x16x32_fp8_fp8(             \
            Af[ks], bq2.x, acc[np * 2], 0, 0, 0);                             \
        acc[np * 2 + 1] = __builtin_amdgcn_mfma_f32_16x16x32_fp8_fp8(         \
            Af[ks], bq2.y, acc[np * 2 + 1], 0, 0, 0);                         \
      }                                                                       \
    }                                                                         \
  }

  GISSUE(0, Bl[0])
  GISSUE(1, Bl[1])

#pragma unroll
  for (int t = 0; t < 4; ++t) {
    f32x4 acc[8];
#pragma unroll
    for (int nf = 0; nf < 8; ++nf) acc[nf] = (f32x4){0.f, 0.f, 0.f, 0.f};

    if (t < 3) { VMBAR4(); } else { VMBAR0(); }   // cur staged (all waves)
    COMPUTE_T(Bl[t & 1])

    // pool accumulate: BN + ReLU over this tile's 128 positions
#pragma unroll
    for (int nf = 0; nf < 8; ++nf) {
      pool0 += fmaxf(acc[nf][0] * sc4.x + sh4.x, 0.f);
      pool1 += fmaxf(acc[nf][1] * sc4.y + sh4.y, 0.f);
      pool2 += fmaxf(acc[nf][2] * sc4.z + sh4.z, 0.f);
      pool3 += fmaxf(acc[nf][3] * sc4.w + sh4.w, 0.f);
    }
    BAR();                              // all waves done reading cur
    if (t + 2 < 4) GISSUE(t + 2, Bl[t & 1])   // refill freed buffer
  }

  // reduce over the 16 positions (r15 lanes)
#pragma unroll
  for (int m = 1; m < 16; m <<= 1) {
    pool0 += __shfl_xor(pool0, m);
    pool1 += __shfl_xor(pool1, m);
    pool2 += __shfl_xor(pool2, m);
    pool3 += __shfl_xor(pool3, m);
  }
  if (r15 == 0) {
    float* dst = pool_part + (size_t)blk * 256 + chbase;
    dst[0] = pool0; dst[1] = pool1; dst[2] = pool2; dst[3] = pool3;
  }
}

// ------- kernel 1 FALLBACK (R8 version): used only if ws too small -------
__global__ __launch_bounds__(1024, 4) void k1_fb(
    const float* __restrict__ x1, const float* __restrict__ x2,
    const u32* __restrict__ Wp,
    const float* __restrict__ scale, const float* __restrict__ shift,
    float* __restrict__ pool_part)
{
  __shared__ __align__(16) char Bl[2][32768];
  const int tid  = threadIdx.x;
  const int wave = tid >> 6;
  const int lane = tid & 63;
  const int r15  = lane & 15;
  const int kg   = lane >> 4;
  const int blk  = blockIdx.x;
  const int b    = blk >> 5;
  const int tile0 = (blk & 31) * 8;
  const float* xb1 = x1 + (size_t)b * C_ * HW_;
  const float* xb2 = x2 + (size_t)b * C_ * HW_;
  const int p2  = tid & 31;
  const int k8  = tid >> 5;
  const int ksL = k8 >> 2;
  const int kgs = k8 & 3;
  const int nfs = p2 >> 3;
  const int L0  = ((2 * p2) & 15) + kgs * 16;
  const int WB0 = (ksL * 2 + (nfs >> 1)) * 1024 + L0 * 16 + (nfs & 1) * 8;
  i64 Af[16];
#pragma unroll
  for (int ks = 0; ks < 16; ++ks)
    Af[ks] = *(const i64*)((const char*)Wp
             + ((ks * 16 + wave) * 64 + kg * 16 + r15) * 8);
  const int chbase = wave * 16 + kg * 4;
  const float4 sc4 = *(const float4*)&scale[chbase];
  const float4 sh4 = *(const float4*)&shift[chbase];
  float pool0 = 0.f, pool1 = 0.f, pool2 = 0.f, pool3 = 0.f;
  float2 gR[8];
#define FISSUE(H, P0)                                                         \
  { const float* s0 = ((H) == 0 ? xb1 : xb2) + (size_t)(k8 * 8) * HW_         \
                      + (P0) + 2 * p2;                                        \
    _Pragma("unroll")                                                         \
    for (int rr = 0; rr < 8; ++rr) gR[rr] = *(const float2*)(s0 + rr * HW_); }
#define FWRITE(H, BUF)                                                        \
  { u32 a0 = 0, a1 = 0, b0 = 0, b1 = 0;                                       \
    a0 = __builtin_amdgcn_cvt_pk_fp8_f32(gR[0].x, gR[1].x, a0, false);        \
    a0 = __builtin_amdgcn_cvt_pk_fp8_f32(gR[2].x, gR[3].x, a0, true);         \
    a1 = __builtin_amdgcn_cvt_pk_fp8_f32(gR[4].x, gR[5].x, a1, false);        \
    a1 = __builtin_amdgcn_cvt_pk_fp8_f32(gR[6].x, gR[7].x, a1, true);         \
    b0 = __builtin_amdgcn_cvt_pk_fp8_f32(gR[0].y, gR[1].y, b0, false);        \
    b0 = __builtin_amdgcn_cvt_pk_fp8_f32(gR[2].y, gR[3].y, b0, true);         \
    b1 = __builtin_amdgcn_cvt_pk_fp8_f32(gR[4].y, gR[5].y, b1, false);        \
    b1 = __builtin_amdgcn_cvt_pk_fp8_f32(gR[6].y, gR[7].y, b1, true);         \
    char* wb = (char*)(BUF) + WB0 + (H) * 16384;                              \
    u32* w0p = (u32*)(wb); w0p[0] = a0; w0p[1] = a1;                          \
    u32* w1p = (u32*)(wb + 16); w1p[0] = b0; w1p[1] = b1; }
#define FCOMP(H, BUF)                                                         \
  { _Pragma("unroll")                                                         \
    for (int ks8 = 0; ks8 < 8; ++ks8) {                                       \
      const int ks = (H) * 8 + ks8;                                           \
      const char* rbase = (const char*)(BUF) + ks * 2048 + lane * 16;         \
      _Pragma("unroll")                                                       \
      for (int np = 0; np < 2; ++np) {                                        \
        i64x2 bq2 = *(const i64x2*)(rbase + np * 1024);                       \
        acc[np * 2] = __builtin_amdgcn_mfma_f32_16x16x32_fp8_fp8(             \
            Af[ks], bq2.x, acc[np * 2], 0, 0, 0);                             \
        acc[np * 2 + 1] = __builtin_amdgcn_mfma_f32_16x16x32_fp8_fp8(         \
            Af[ks], bq2.y, acc[np * 2 + 1], 0, 0, 0);                         \
      } } }
  FISSUE(0, tile0 * 64) FWRITE(0, Bl[0])
  FISSUE(1, tile0 * 64) FWRITE(1, Bl[0])
  __syncthreads();
  for (int tt = 0; tt < 8; ++tt) {
    f32x4 acc[4];
#pragma unroll
    for (int nf = 0; nf < 4; ++nf) acc[nf] = (f32x4){0.f, 0.f, 0.f, 0.f};
    const int p0n = (tile0 + tt + 1) * 64;
    const bool more = (tt + 1 < 8);
    const char* cb = Bl[tt & 1];
    char* nxt = Bl[(tt + 1) & 1];
    if (more) FISSUE(0, p0n)
    FCOMP(0, cb)
    if (more) { FWRITE(0, nxt) FISSUE(1, p0n) }
    FCOMP(1, cb)
    if (more) FWRITE(1, nxt)
#pragma unroll
    for (int nf = 0; nf < 4; ++nf) {
      pool0 += fmaxf(acc[nf][0] * sc4.x + sh4.x, 0.f);
      pool1 += fmaxf(acc[nf][1] * sc4.y + sh4.y, 0.f);
      pool2 += fmaxf(acc[nf][2] * sc4.z + sh4.z, 0.f);
      pool3 += fmaxf(acc[nf][3] * sc4.w + sh4.w, 0.f);
    }
    __syncthreads();
  }
#pragma unroll
  for (int m = 1; m < 16; m <<= 1) {
    pool0 += __shfl_xor(pool0, m);
    pool1 += __shfl_xor(pool1, m);
    pool2 += __shfl_xor(pool2, m);
    pool3 += __shfl_xor(pool3, m);
  }
  if (r15 == 0) {
    float* dst = pool_part + (size_t)blk * 256 + chbase;
    dst[0] = pool0; dst[1] = pool1; dst[2] = pool2; dst[3] = pool3;
  }
}

// -------- kernel 2: tiny MLPs -> per-(b,c) 3x3 kernels + attn coefs --------
__global__ __launch_bounds__(256) void k2_small(
    const float* __restrict__ pool_part,
    const float* __restrict__ w_cg1, const float* __restrict__ w_cg2,
    const float* __restrict__ w_ag1, const float* __restrict__ w_ag2,
    float* __restrict__ cw, float* __restrict__ coef)
{
  __shared__ float pl[256];
  __shared__ float hl[64];
  const int bi = blockIdx.x;
  const int b = bi / 10, j = bi % 10;
  const int t = threadIdx.x;
  float s = 0.f;
  const float* base = pool_part + (size_t)b * 32 * 256 + t;
  for (int blk = 0; blk < 32; ++blk) s += base[blk * 256];   // fixed order
  pl[t] = s * (1.0f / 16384.0f);
  __syncthreads();
  if (j < 9) {
    if (t < 64) {
      float h = 0.f;
      for (int i = 0; i < 256; ++i) h += pl[i] * w_cg1[t * 256 + i];
      hl[t] = fmaxf(h, 0.f);
    }
    __syncthreads();
    const int o = t * 9 + j;
    float acc = 0.f;
    for (int jj = 0; jj < 64; ++jj) acc += hl[jj] * w_cg2[o * 64 + jj];
    cw[b * 2304 + o] = acc;
  } else {
    if (t < 64) {
      float a = 0.f;
      for (int i = 0; i < 256; ++i) a += pl[i] * w_ag1[t * 256 + i];
      hl[t] = fmaxf(a, 0.f);
    }
    __syncthreads();
    if (t < 2) {
      float acc = 0.f;
      for (int jj = 0; jj < 64; ++jj) acc += hl[jj] * w_ag2[t * 64 + jj];
      coef[b * 2 + t] = 0.25f / (1.0f + expf(-acc));   // 0.25 = L_S * L_C
    }
  }
}

// -------- kernel 3: depthwise 3x3 (same kernel on x1 & x2) + combine --------
__global__ __launch_bounds__(256) void k3_dynconv(
    const float* __restrict__ x1, const float* __restrict__ x2,
    const float* __restrict__ cw, const float* __restrict__ coef,
    float* __restrict__ out)
{
  __shared__ float t1[34 * 128];
  __shared__ float t2[34 * 128];
  const int tid   = threadIdx.x;
  const int blk   = blockIdx.x;
  const int strip = blk & 3;
  const int c     = (blk >> 2) & 255;
  const int b     = blk >> 10;
  const int h0    = strip * 32;

  const size_t plane = ((size_t)b * C_ + c) * HW_;
  const float* p1 = x1 + plane;
  const float* p2 = x2 + plane;

  float tp[9];
#pragma unroll
  for (int e = 0; e < 9; ++e) tp[e] = cw[(b * C_ + c) * 9 + e];
  const float c1 = coef[b * 2 + 0];
  const float c2 = coef[b * 2 + 1];

  for (int f = tid; f < 1088; f += 256) {
    int row = f >> 5;
    int c4  = (f & 31) << 2;
    int gh  = h0 - 1 + row;
    float4 v1 = make_float4(0.f, 0.f, 0.f, 0.f), v2 = v1;
    if (gh >= 0 && gh < 128) {
      v1 = *(const float4*)&p1[gh * 128 + c4];
      v2 = *(const float4*)&p2[gh * 128 + c4];
    }
    *(float4*)&t1[row * 128 + c4] = v1;
    *(float4*)&t2[row * 128 + c4] = v2;
  }
  __syncthreads();

  for (int i = 0; i < 16; ++i) {
    int q   = tid + i * 256;
    int r   = q >> 7;
    int col = q & 127;
    int lr  = r + 1;
    const bool lok = col > 0, rok = col < 127;
    float d1 = 0.f, d2 = 0.f;
#pragma unroll
    for (int dy = 0; dy < 3; ++dy) {
      const float* row1 = &t1[(lr - 1 + dy) * 128];
      const float* row2 = &t2[(lr - 1 + dy) * 128];
      float a1v = lok ? row1[col - 1] : 0.f;
      float b1v = row1[col];
      float e1v = rok ? row1[col + 1] : 0.f;
      float a2v = lok ? row2[col - 1] : 0.f;
      float b2v = row2[col];
      float e2v = rok ? row2[col + 1] : 0.f;
      d1 += a1v * tp[dy * 3 + 0] + b1v * tp[dy * 3 + 1] + e1v * tp[dy * 3 + 2];
      d2 += a2v * tp[dy * 3 + 0] + b2v * tp[dy * 3 + 1] + e2v * tp[dy * 3 + 2];
    }
    float v1 = t1[lr * 128 + col];
    float v2 = t2[lr * 128 + col];
    out[plane + (size_t)(h0 + r) * 128 + col] = 0.5f * (v1 + v2) + c1 * d1 + c2 * d2;
  }
}

extern "C" void kernel_launch(void* const* d_in, const int* in_sizes, int n_in,
                              void* d_out, int out_size, void* d_ws, size_t ws_size,
                              hipStream_t stream) {
  const float* x1    = (const float*)d_in[0];
  const float* x2    = (const float*)d_in[1];
  const float* w_fe  = (const float*)d_in[2];
  const float* gamma = (const float*)d_in[3];
  const float* beta  = (const float*)d_in[4];
  const float* mean  = (const float*)d_in[5];
  const float* var   = (const float*)d_in[6];
  const float* w_cg1 = (const float*)d_in[7];
  const float* w_cg2 = (const float*)d_in[8];
  const float* w_ag1 = (const float*)d_in[9];
  const float* w_ag2 = (const float*)d_in[10];
  float* out = (float*)d_out;

  char* ws = (char*)d_ws;
  u32* Wp          = (u32*)(ws);                           // [0, 131072)
  float* scale     = (float*)(ws + 131072);                // 1 KB
  float* shift     = (float*)(ws + 132096);                // 1 KB
  float* pool_part = (float*)(ws + 133120);                // 256 KB
  float* cw        = (float*)(ws + 395264);                // 73728 B
  float* coef      = (float*)(ws + 468992);                // 64 B
  char* Xq         = ws + 524288;                          // 64 MB tile images
  const size_t NEED = 524288 + (size_t)8 * 128 * 65536;    // 67,633,152

  k0_prep<<<128, 256, 0, stream>>>(w_fe, gamma, beta, mean, var, Wp, scale, shift);
  if (ws_size >= NEED) {
    kq_pack<<<1024, 256, 0, stream>>>(x1, x2, Xq);
    k1_gemm_pool<<<256, 1024, 0, stream>>>(Xq, Wp, scale, shift, pool_part);
  } else {
    k1_fb<<<256, 1024, 0, stream>>>(x1, x2, Wp, scale, shift, pool_part);
  }
  k2_small<<<80, 256, 0, stream>>>(pool_part, w_cg1, w_cg2, w_ag1, w_ag2, cw, coef);
  k3_dynconv<<<8192, 256, 0, stream>>>(x1, x2, cw, coef, out);
}

// Round 12
// 152.288 us; speedup vs baseline: 1.4640x; 1.4502x over previous
//
#include <hip/hip_runtime.h>
#include <stdint.h>
#include <math.h>

#define HW_ 16384   // H*W = 128*128
#define C_  256
#define NT  4       // tiles per block (each tile = 128 positions)

typedef long i64;
typedef float f32x4 __attribute__((ext_vector_type(4)));
typedef unsigned int u32;

// barrier WITHOUT vmcnt drain: orders LDS only; prefetch loads stay in flight
#define BARRIER_LGKM() asm volatile("s_waitcnt lgkmcnt(0)\n\ts_barrier" ::: "memory")

// -------- kernel 0: prep (W -> fp8 e4m3 in MFMA-fragment order, BN consts) --
// Wp byte layout: idx = ((ks*16 + mf)*64 + kg*16 + r15)*8 + e
__global__ __launch_bounds__(256) void k0_prep(
    const float* __restrict__ w_fe, const float* __restrict__ gamma,
    const float* __restrict__ beta, const float* __restrict__ mean,
    const float* __restrict__ var, u32* __restrict__ Wp,
    float* __restrict__ scale, float* __restrict__ shift)
{
  int i = blockIdx.x * 256 + threadIdx.x;
  if (i < 32768) {                     // one u32 = 4 fp8 bytes
    int e0  = (i & 1) * 4;
    int r15 = (i >> 1) & 15;
    int kg  = (i >> 5) & 3;
    int mf  = (i >> 7) & 15;
    int ks  = i >> 11;
    int row = mf * 16 + r15;
    int k   = ks * 32 + kg * 8 + e0;   // 4 consecutive k
    const float* src = w_fe + row * 512 + k;
    u32 w = 0;
    w = __builtin_amdgcn_cvt_pk_fp8_f32(src[0], src[1], w, false);
    w = __builtin_amdgcn_cvt_pk_fp8_f32(src[2], src[3], w, true);
    Wp[i] = w;
  }
  if (i < 256) {
    float sc = gamma[i] * rsqrtf(var[i] + 1e-5f);
    scale[i] = sc;
    shift[i] = beta[i] - mean[i] * sc;
  }
}

// ------- kernel 1: persistent-W fp8 MFMA GEMM + BN + ReLU + pool -------
// 16 waves; wave w = m-frag w. A-frags (fp8, 32 regs) persistent. Tile = 128
// pos x 512 k fp8 in LDS, layout [K-octet 0..63][p 0..127][e 0..7] with XOR
// swizzle (p*8 ^ (K&3)<<5): b64 frag reads 4-way, b32 stage writes 8-way.
// Staging: 4x float4 per sub-unit (16 live regs, no spill); per-instruction
// global read granule = 2 x 512 B (vs R8's 2 x 256 B) -- the experiment.
// Double-buffered, lgkm-only barrier (loads stay in flight). Grid: 256x1024.
__global__ __launch_bounds__(1024, 4) void k1_gemm_pool(
    const float* __restrict__ x1, const float* __restrict__ x2,
    const u32* __restrict__ Wp,
    const float* __restrict__ scale, const float* __restrict__ shift,
    float* __restrict__ pool_part)
{
  __shared__ __align__(16) char Bl[2][65536];   // 2 x 64KB

  const int tid  = threadIdx.x;
  const int wave = tid >> 6;        // = mf
  const int lane = tid & 63;
  const int r15  = lane & 15;
  const int kg   = lane >> 4;
  const int blk  = blockIdx.x;
  const int b    = blk >> 5;                 // batch
  const int t0   = (blk & 31) * NT;

  const float* xb1 = x1 + (size_t)b * C_ * HW_;
  const float* xb2 = x2 + (size_t)b * C_ * HW_;

  // staging decomposition: thread owns (octet o, pos-quad q) per k-half
  const int o   = tid >> 5;          // 0..31 octet within half
  const int q   = tid & 31;          // pos-quad
  const int pq  = q * 4;             // pos base 0..124
  const int wq  = (q * 32) ^ ((o & 3) << 5);   // swizzled pos-part of write addr

  // frag-read constant: swizzled lane offset within an octet block
  const int rb_off = (r15 * 8) ^ (kg << 5);

  // ---- A-frags once for this wave (16 x i64 = 32 regs) ----
  i64 Af[16];
#pragma unroll
  for (int ks = 0; ks < 16; ++ks)
    Af[ks] = *(const i64*)((const char*)Wp
             + ((ks * 16 + wave) * 64 + kg * 16 + r15) * 8);

  const int chbase = wave * 16 + kg * 4;
  const float4 sc4 = *(const float4*)&scale[chbase];
  const float4 sh4 = *(const float4*)&shift[chbase];

  float pool0 = 0.f, pool1 = 0.f, pool2 = 0.f, pool3 = 0.f;

  f32x4 gU[4];   // staging sub-unit: 4 rows x 4 pos (16 regs live)

// Load sub-unit (H half, S row-group) of tile at base pos P0.
// Per instruction: 64 lanes x 16 B = 2 chunks of 512 B (one per o-half).
#define ISSUE_U(H, S, P0)                                                     \
  {                                                                           \
    const float* s0 = ((H) == 0 ? xb1 : xb2)                                  \
                      + (size_t)(o * 8 + (S) * 4) * HW_ + (P0) + pq;          \
    _Pragma("unroll")                                                         \
    for (int r = 0; r < 4; ++r) gU[r] = *(const f32x4*)(s0 + r * HW_);        \
  }

// Convert sub-unit to fp8, write 4 x b32 (w-half S of 4 positions).
#define WRITE_U(H, S, BUF)                                                    \
  {                                                                           \
    char* wb = (char*)(BUF) + ((H) * 32 + o) * 1024 + wq + (S) * 4;           \
    _Pragma("unroll")                                                         \
    for (int j = 0; j < 4; ++j) {                                             \
      u32 w = 0;                                                              \
      w = __builtin_amdgcn_cvt_pk_fp8_f32(gU[0][j], gU[1][j], w, false);      \
      w = __builtin_amdgcn_cvt_pk_fp8_f32(gU[2][j], gU[3][j], w, true);       \
      *(u32*)(wb + j * 8) = w;                                                \
    }                                                                         \
  }

// Quarter-compute: 4 ks x 8 nf = 32 b64 reads + 32 MFMA.
#define COMPUTE_Q(QK, BUF)                                                    \
  {                                                                           \
    _Pragma("unroll")                                                         \
    for (int ks = (QK) * 4; ks < (QK) * 4 + 4; ++ks) {                        \
      const char* rb = (const char*)(BUF) + (ks * 4 + kg) * 1024 + rb_off;    \
      _Pragma("unroll")                                                       \
      for (int nf = 0; nf < 8; ++nf) {                                        \
        i64 bq = *(const i64*)(rb + nf * 128);                                \
        acc[nf] = __builtin_amdgcn_mfma_f32_16x16x32_fp8_fp8(                 \
            Af[ks], bq, acc[nf], 0, 0, 0);                                    \
      }                                                                       \
    }                                                                         \
  }

  // ---- prologue: stage tile t0 into buf 0 ----
  ISSUE_U(0, 0, t0 * 128) WRITE_U(0, 0, Bl[0])
  ISSUE_U(0, 1, t0 * 128) WRITE_U(0, 1, Bl[0])
  ISSUE_U(1, 0, t0 * 128) WRITE_U(1, 0, Bl[0])
  ISSUE_U(1, 1, t0 * 128) WRITE_U(1, 1, Bl[0])
  __syncthreads();

  for (int tt = 0; tt < NT; ++tt) {
    f32x4 acc[8];
#pragma unroll
    for (int nf = 0; nf < 8; ++nf) acc[nf] = (f32x4){0.f, 0.f, 0.f, 0.f};

    const int p1 = (t0 + tt + 1) * 128;
    const bool more = (tt + 1 < NT);
    const char* cb = Bl[tt & 1];
    char* nxt = Bl[(tt + 1) & 1];

    if (more) ISSUE_U(0, 0, p1)
    COMPUTE_Q(0, cb)
    if (more) { WRITE_U(0, 0, nxt) ISSUE_U(0, 1, p1) }
    COMPUTE_Q(1, cb)
    if (more) { WRITE_U(0, 1, nxt) ISSUE_U(1, 0, p1) }
    COMPUTE_Q(2, cb)
    if (more) { WRITE_U(1, 0, nxt) ISSUE_U(1, 1, p1) }
    COMPUTE_Q(3, cb)
    if (more) WRITE_U(1, 1, nxt)

    // pool accumulate: BN + ReLU over this tile's 128 positions
#pragma unroll
    for (int nf = 0; nf < 8; ++nf) {
      pool0 += fmaxf(acc[nf][0] * sc4.x + sh4.x, 0.f);
      pool1 += fmaxf(acc[nf][1] * sc4.y + sh4.y, 0.f);
      pool2 += fmaxf(acc[nf][2] * sc4.z + sh4.z, 0.f);
      pool3 += fmaxf(acc[nf][3] * sc4.w + sh4.w, 0.f);
    }
    BARRIER_LGKM();                    // loads stay in flight across barrier
  }

  // reduce over the 16 positions (r15 lanes)
#pragma unroll
  for (int m = 1; m < 16; m <<= 1) {
    pool0 += __shfl_xor(pool0, m);
    pool1 += __shfl_xor(pool1, m);
    pool2 += __shfl_xor(pool2, m);
    pool3 += __shfl_xor(pool3, m);
  }
  if (r15 == 0) {
    float* dst = pool_part + (size_t)blk * 256 + chbase;
    dst[0] = pool0; dst[1] = pool1; dst[2] = pool2; dst[3] = pool3;
  }
}

// -------- kernel 2: tiny MLPs -> per-(b,c) 3x3 kernels + attn coefs --------
// grid 80 = 8 batches x 10 jobs (j=0..8: tap j of all 256 channels; j=9: coef)
__global__ __launch_bounds__(256) void k2_small(
    const float* __restrict__ pool_part,
    const float* __restrict__ w_cg1, const float* __restrict__ w_cg2,
    const float* __restrict__ w_ag1, const float* __restrict__ w_ag2,
    float* __restrict__ cw, float* __restrict__ coef)
{
  __shared__ float pl[256];
  __shared__ float hl[64];
  const int bi = blockIdx.x;
  const int b = bi / 10, j = bi % 10;
  const int t = threadIdx.x;
  float s = 0.f;
  const float* base = pool_part + (size_t)b * 32 * 256 + t;
  for (int blk = 0; blk < 32; ++blk) s += base[blk * 256];   // fixed order
  pl[t] = s * (1.0f / 16384.0f);
  __syncthreads();
  if (j < 9) {
    if (t < 64) {
      float h = 0.f;
      for (int i = 0; i < 256; ++i) h += pl[i] * w_cg1[t * 256 + i];
      hl[t] = fmaxf(h, 0.f);
    }
    __syncthreads();
    const int o = t * 9 + j;                 // row of w_cg2 = c*9 + tap
    float acc = 0.f;
    for (int jj = 0; jj < 64; ++jj) acc += hl[jj] * w_cg2[o * 64 + jj];
    cw[b * 2304 + o] = acc;
  } else {
    if (t < 64) {
      float a = 0.f;
      for (int i = 0; i < 256; ++i) a += pl[i] * w_ag1[t * 256 + i];
      hl[t] = fmaxf(a, 0.f);
    }
    __syncthreads();
    if (t < 2) {
      float acc = 0.f;
      for (int jj = 0; jj < 64; ++jj) acc += hl[jj] * w_ag2[t * 64 + jj];
      coef[b * 2 + t] = 0.25f / (1.0f + expf(-acc));   // 0.25 = L_S * L_C
    }
  }
}

// -------- kernel 3: depthwise 3x3 (same kernel on x1 & x2) + combine --------
__global__ __launch_bounds__(256) void k3_dynconv(
    const float* __restrict__ x1, const float* __restrict__ x2,
    const float* __restrict__ cw, const float* __restrict__ coef,
    float* __restrict__ out)
{
  __shared__ float t1[34 * 128];
  __shared__ float t2[34 * 128];
  const int tid   = threadIdx.x;
  const int blk   = blockIdx.x;
  const int strip = blk & 3;
  const int c     = (blk >> 2) & 255;
  const int b     = blk >> 10;
  const int h0    = strip * 32;

  const size_t plane = ((size_t)b * C_ + c) * HW_;
  const float* p1 = x1 + plane;
  const float* p2 = x2 + plane;

  float tp[9];
#pragma unroll
  for (int e = 0; e < 9; ++e) tp[e] = cw[(b * C_ + c) * 9 + e];
  const float c1 = coef[b * 2 + 0];
  const float c2 = coef[b * 2 + 1];

  for (int f = tid; f < 1088; f += 256) {
    int row = f >> 5;
    int c4  = (f & 31) << 2;
    int gh  = h0 - 1 + row;
    float4 v1 = make_float4(0.f, 0.f, 0.f, 0.f), v2 = v1;
    if (gh >= 0 && gh < 128) {
      v1 = *(const float4*)&p1[gh * 128 + c4];
      v2 = *(const float4*)&p2[gh * 128 + c4];
    }
    *(float4*)&t1[row * 128 + c4] = v1;
    *(float4*)&t2[row * 128 + c4] = v2;
  }
  __syncthreads();

  for (int i = 0; i < 16; ++i) {
    int q   = tid + i * 256;
    int r   = q >> 7;
    int col = q & 127;
    int lr  = r + 1;
    const bool lok = col > 0, rok = col < 127;
    float d1 = 0.f, d2 = 0.f;
#pragma unroll
    for (int dy = 0; dy < 3; ++dy) {
      const float* row1 = &t1[(lr - 1 + dy) * 128];
      const float* row2 = &t2[(lr - 1 + dy) * 128];
      float a1v = lok ? row1[col - 1] : 0.f;
      float b1v = row1[col];
      float e1v = rok ? row1[col + 1] : 0.f;
      float a2v = lok ? row2[col - 1] : 0.f;
      float b2v = row2[col];
      float e2v = rok ? row2[col + 1] : 0.f;
      d1 += a1v * tp[dy * 3 + 0] + b1v * tp[dy * 3 + 1] + e1v * tp[dy * 3 + 2];
      d2 += a2v * tp[dy * 3 + 0] + b2v * tp[dy * 3 + 1] + e2v * tp[dy * 3 + 2];
    }
    float v1 = t1[lr * 128 + col];
    float v2 = t2[lr * 128 + col];
    out[plane + (size_t)(h0 + r) * 128 + col] = 0.5f * (v1 + v2) + c1 * d1 + c2 * d2;
  }
}

extern "C" void kernel_launch(void* const* d_in, const int* in_sizes, int n_in,
                              void* d_out, int out_size, void* d_ws, size_t ws_size,
                              hipStream_t stream) {
  const float* x1    = (const float*)d_in[0];
  const float* x2    = (const float*)d_in[1];
  const float* w_fe  = (const float*)d_in[2];
  const float* gamma = (const float*)d_in[3];
  const float* beta  = (const float*)d_in[4];
  const float* mean  = (const float*)d_in[5];
  const float* var   = (const float*)d_in[6];
  const float* w_cg1 = (const float*)d_in[7];
  const float* w_cg2 = (const float*)d_in[8];
  const float* w_ag1 = (const float*)d_in[9];
  const float* w_ag2 = (const float*)d_in[10];
  float* out = (float*)d_out;

  // workspace layout (~470 KB)
  char* ws = (char*)d_ws;
  u32* Wp          = (u32*)(ws);                           // [0, 131072)
  float* scale     = (float*)(ws + 131072);                // 1 KB
  float* shift     = (float*)(ws + 132096);                // 1 KB
  float* pool_part = (float*)(ws + 133120);                // 256*256*4 = 256 KB
  float* cw        = (float*)(ws + 395264);                // 73728 B
  float* coef      = (float*)(ws + 468992);                // 64 B

  k0_prep<<<128, 256, 0, stream>>>(w_fe, gamma, beta, mean, var, Wp, scale, shift);
  k1_gemm_pool<<<256, 1024, 0, stream>>>(x1, x2, Wp, scale, shift, pool_part);
  k2_small<<<80, 256, 0, stream>>>(pool_part, w_cg1, w_cg2, w_ag1, w_ag2, cw, coef);
  k3_dynconv<<<8192, 256, 0, stream>>>(x1, x2, cw, coef, out);
}